// Round 22
// baseline (121.571 us; speedup 1.0000x reference)
//
#include <hip/hip_runtime.h>

#define TEMP 5.656854249492380195f   // sqrt(32)
#define EPSG 1e-10f

// K1 GEMM geometry: M-tile 64 (8 b x 8 v), N 64 (q|k), K chunk 64, 8 chunks.
#define XSTR 68                      // x-tile row stride (floats)
#define WSTR 64                      // w-tile row stride

// ---------- Single fused kernel ---------------------------------------------
// Phase A: proj GEMM + pair argmax. NEW: 8x4 micro-tile on 128 compute
//          threads (rows ctm+8j, strided -> conflict-free), 12 ds_read_b128
//          per 128 FMAs (was 8 per 64) -> 25% less LDS traffic. Per-element
//          FP chains identical -> selections unchanged.
// Phase B: comb staging + q2 GEMM + rule argmax (verbatim R21).
// Phase C: MLP + output write (verbatim R21).
__launch_bounds__(256, 2)
__global__ void fused_kernel(const float* __restrict__ hidden,
                             const float* __restrict__ u_var,
                             const float* __restrict__ u_rule,
                             const float* __restrict__ Wq,
                             const float* __restrict__ bq,
                             const float* __restrict__ Wk,
                             const float* __restrict__ bk,
                             const float* __restrict__ rule_emb,
                             const float* __restrict__ Wk2,
                             const float* __restrict__ bk2,
                             const float* __restrict__ Wq2,
                             const float* __restrict__ bq2,
                             const float* __restrict__ W1,
                             const float* __restrict__ W2,
                             float* __restrict__ outbuf) {
    const int tid = threadIdx.x;
    const int b0  = blockIdx.x * 8;

    __shared__ float4 smem4[(64 * XSTR + 64 * WSTR) / 4];   // 33.8 KB
    float* smem = reinterpret_cast<float*>(smem4);
    float* xt = smem;
    float* wt = smem + 64 * XSTR;
    __shared__ float4 hm4[1024];          // 16 KB hmean; part4 aliases [0:256)
    float* hm = reinterpret_cast<float*>(hm4);
    float4* part4 = hm4;                  // 4 KB, live only after hm dies
    __shared__ float  sk2[512];           // 2 KB
    __shared__ float  s_q2[8][32];        // 1 KB
    __shared__ int    ssel[8];
    __shared__ int    s_rsel[8];

    // per-block k2 = rule_emb @ Wk2 + bk2 (identical formula)
    for (int t = tid; t < 512; t += 256) {
        int r = t >> 5, d = t & 31;
        float acc = bk2[d];
        for (int h = 0; h < 64; ++h)
            acc += rule_emb[r * 64 + h] * Wk2[h * 32 + d];
        sk2[t] = acc;
    }

    const int w    = tid >> 6;
    const int lane = tid & 63;

    // compute-phase mapping (tid < 128): 8x4 micro-tile, strided rows
    const int ctn = tid & 15;             // col group (cols ctn*4..+3)
    const int ctm = (tid >> 4) & 7;       // row base; rows ctm + 8j, j=0..7

    float4 acc[8];
    #pragma unroll
    for (int j = 0; j < 8; ++j) acc[j] = make_float4(0.f, 0.f, 0.f, 0.f);

    for (int c = 0; c < 8; ++c) {
        #pragma unroll
        for (int p = 0; p < 4; ++p) {
            int f   = p * 256 + tid;
            int row = f >> 4;
            int c4  = f & 15;
            int bb  = row >> 3, v = row & 7;
            float4 val = *reinterpret_cast<const float4*>(
                hidden + (size_t)(b0 + bb) * 4096 + v * 512 + c * 64 + c4 * 4);
            *reinterpret_cast<float4*>(&xt[row * XSTR + c4 * 4]) = val;
        }
        #pragma unroll
        for (int p = 0; p < 4; ++p) {
            int f  = p * 256 + tid;
            int k  = f >> 4;
            int n4 = f & 15;
            int h  = c * 64 + k;
            const float* src = (n4 < 8) ? (Wq + h * 32 + n4 * 4)
                                        : (Wk + h * 32 + (n4 - 8) * 4);
            *reinterpret_cast<float4*>(&wt[k * WSTR + n4 * 4]) =
                *reinterpret_cast<const float4*>(src);
        }
        __syncthreads();

        if (tid < 128) {
            #pragma unroll 2
            for (int k4 = 0; k4 < 16; ++k4) {
                float4 w0 = *reinterpret_cast<const float4*>(&wt[(k4 * 4 + 0) * WSTR + ctn * 4]);
                float4 w1 = *reinterpret_cast<const float4*>(&wt[(k4 * 4 + 1) * WSTR + ctn * 4]);
                float4 w2 = *reinterpret_cast<const float4*>(&wt[(k4 * 4 + 2) * WSTR + ctn * 4]);
                float4 w3 = *reinterpret_cast<const float4*>(&wt[(k4 * 4 + 3) * WSTR + ctn * 4]);
                #pragma unroll
                for (int j = 0; j < 8; ++j) {
                    float4 x = *reinterpret_cast<const float4*>(
                        &xt[(ctm + 8 * j) * XSTR + k4 * 4]);
                    acc[j].x += x.x * w0.x + x.y * w1.x + x.z * w2.x + x.w * w3.x;
                    acc[j].y += x.x * w0.y + x.y * w1.y + x.z * w2.y + x.w * w3.y;
                    acc[j].z += x.x * w0.z + x.y * w1.z + x.z * w2.z + x.w * w3.z;
                    acc[j].w += x.x * w0.w + x.y * w1.w + x.z * w2.w + x.w * w3.w;
                }
            }
        }

        // hmean partial -> LDS (same adds/order as frozen kernel)
        {
            int bb = tid >> 5, hg = tid & 31;
            float m0 = 0.f, m1 = 0.f;
            #pragma unroll
            for (int v = 0; v < 8; ++v) {
                float2 x2 = *reinterpret_cast<const float2*>(&xt[(bb * 8 + v) * XSTR + hg * 2]);
                m0 += x2.x; m1 += x2.y;
            }
            hm[bb * 512 + c * 64 + hg * 2]     = m0 * 0.125f;
            hm[bb * 512 + c * 64 + hg * 2 + 1] = m1 * 0.125f;
        }
        __syncthreads();
    }

    // epilogue: bias + scores to LDS (aliases xt region), 128 threads
    if (tid < 128) {
        const float* bsrc = (ctn < 8) ? (bq + ctn * 4) : (bk + (ctn - 8) * 4);
        float4 bias4 = *reinterpret_cast<const float4*>(bsrc);
        float* sq = smem;
        #pragma unroll
        for (int j = 0; j < 8; ++j) {
            float4 r;
            r.x = acc[j].x + bias4.x; r.y = acc[j].y + bias4.y;
            r.z = acc[j].z + bias4.z; r.w = acc[j].w + bias4.w;
            *reinterpret_cast<float4*>(&sq[(ctm + 8 * j) * XSTR + ctn * 4]) = r;
        }
    }
    __syncthreads();

    {
        const float* sq = smem;
        #pragma unroll
        for (int half = 0; half < 2; ++half) {
            const int bb = w + half * 4;
            const int b  = b0 + bb;
            const int i = lane >> 3, j = lane & 7;
            float s = 0.f;
            #pragma unroll
            for (int d4 = 0; d4 < 8; ++d4) {
                float4 qv = *reinterpret_cast<const float4*>(&sq[(bb * 8 + i) * XSTR + d4 * 4]);
                float4 kv = *reinterpret_cast<const float4*>(&sq[(bb * 8 + j) * XSTR + 32 + d4 * 4]);
                s += qv.x * kv.x + qv.y * kv.y + qv.z * kv.z + qv.w * kv.w;
            }
            s /= TEMP;
            float u = u_var[(size_t)b * 64 + lane];
            float g = -logf(-logf(u + EPSG) + EPSG);
            float pm = s + g;
            int idx = lane;
            #pragma unroll
            for (int off = 32; off >= 1; off >>= 1) {
                float pv = __shfl_xor(pm, off);
                int   pi = __shfl_xor(idx, off);
                if (pv > pm || (pv == pm && pi < idx)) { pm = pv; idx = pi; }
            }
            if (lane == 0) ssel[bb] = idx;
        }
    }
    __syncthreads();   // scores consumed; ssel visible

    // ---- stage comb[8][1024] into the dead xt/wt region ----
    {
        float* comb = smem;
        const float4* h4 = reinterpret_cast<const float4*>(hidden);
        #pragma unroll
        for (int p = 0; p < 8; ++p) {
            int f    = p * 256 + tid;      // 2048 float4 total
            int bb   = f >> 8, idx = f & 255;
            int half = idx >> 7, cc = idx & 127;
            int sv   = ssel[bb];
            int row  = half ? (sv >> 3) : (sv & 7);
            reinterpret_cast<float4*>(comb)[bb * 256 + idx] =
                h4[((size_t)(b0 + bb) * 8 + row) * 128 + cc];
        }
    }
    __syncthreads();

    // ---- q2 GEMM (verbatim R18 FP order) + rule argmax ----
    {
        const float* comb = smem;
        const int d4 = tid & 7, s = tid >> 3;
        float4 qa[8];
        #pragma unroll
        for (int bb = 0; bb < 8; ++bb) qa[bb] = make_float4(0.f, 0.f, 0.f, 0.f);

        for (int kt = 0; kt < 6; ++kt) {
            float4 wv[8];
            #pragma unroll
            for (int j = 0; j < 8; ++j)
                wv[j] = *reinterpret_cast<const float4*>(
                    Wq2 + (size_t)(kt * 256 + s * 8 + j) * 32 + d4 * 4);
            #pragma unroll
            for (int bb = 0; bb < 8; ++bb) {
                const float* xsrc = (kt < 4) ? &comb[bb * 1024 + kt * 256]
                                             : &hm[bb * 512 + (kt - 4) * 256];
                #pragma unroll
                for (int j = 0; j < 8; ++j) {
                    float x = xsrc[s * 8 + j];
                    qa[bb].x += x * wv[j].x;
                    qa[bb].y += x * wv[j].y;
                    qa[bb].z += x * wv[j].z;
                    qa[bb].w += x * wv[j].w;
                }
            }
        }
        #pragma unroll
        for (int off = 8; off < 64; off <<= 1) {
            #pragma unroll
            for (int bb = 0; bb < 8; ++bb) {
                qa[bb].x += __shfl_xor(qa[bb].x, off);
                qa[bb].y += __shfl_xor(qa[bb].y, off);
                qa[bb].z += __shfl_xor(qa[bb].z, off);
                qa[bb].w += __shfl_xor(qa[bb].w, off);
            }
        }
        __syncthreads();   // hm fully consumed by ALL threads before aliasing
        if ((s & 7) == 0) {
            #pragma unroll
            for (int bb = 0; bb < 8; ++bb)
                part4[(size_t)(tid >> 6) * 64 + bb * 8 + d4] = qa[bb];
        }
    }
    __syncthreads();
    {
        const int bb = tid >> 5, col = tid & 31;
        float q2 = bq2[col];
        #pragma unroll
        for (int wv2 = 0; wv2 < 4; ++wv2) {
            const float* pf = reinterpret_cast<const float*>(
                &part4[(size_t)wv2 * 64 + bb * 8 + (col >> 2)]);
            q2 += pf[col & 3];
        }
        s_q2[bb][col] = q2;
    }
    __syncthreads();
    if (tid < 128) {
        const int bb = tid >> 4, r = tid & 15;
        const int b = b0 + bb;
        float sc = 0.f;
        #pragma unroll
        for (int d = 0; d < 32; ++d) sc += s_q2[bb][d] * sk2[r * 32 + d];
        sc /= TEMP;
        float u = u_rule[(size_t)b * 16 + r];
        float g = -logf(-logf(u + EPSG) + EPSG);
        float pm = sc + g;
        int idx = r;
        #pragma unroll
        for (int off = 8; off >= 1; off >>= 1) {
            float pv = __shfl_xor(pm, off, 16);
            int   pi = __shfl_xor(idx, off, 16);
            if (pv > pm || (pv == pm && pi < idx)) { pm = pv; idx = pi; }
        }
        if (r == 0) s_rsel[bb] = idx;
    }
    __syncthreads();

    // ---- Phase C: MLP + output write; wave w handles bb = w and w+4 -------
    {
        const float* comb = smem;
        #pragma unroll
        for (int half = 0; half < 2; ++half) {
            const int bb = w + half * 4;
            const int b  = b0 + bb;
            const int sv = ssel[bb];
            const int js = sv & 7;
            const int r  = s_rsel[bb];

            const int e4 = lane & 3;
            const int s  = lane >> 2;
            const float* cb  = comb + bb * 1024;
            const float* w1p = W1 + (size_t)r * 16384 + e4 * 4;

            float4 h4 = make_float4(0.f, 0.f, 0.f, 0.f);
            #pragma unroll 8
            for (int i = 0; i < 64; ++i) {
                int rr = i * 16 + s;
                float cv = cb[rr];
                float4 wv4 = *reinterpret_cast<const float4*>(w1p + (size_t)rr * 16);
                h4.x += cv * wv4.x; h4.y += cv * wv4.y;
                h4.z += cv * wv4.z; h4.w += cv * wv4.w;
            }
            #pragma unroll
            for (int off = 4; off <= 32; off <<= 1) {
                h4.x += __shfl_xor(h4.x, off);
                h4.y += __shfl_xor(h4.y, off);
                h4.z += __shfl_xor(h4.z, off);
                h4.w += __shfl_xor(h4.w, off);
            }
            h4.x = fmaxf(h4.x, 0.f); h4.y = fmaxf(h4.y, 0.f);
            h4.z = fmaxf(h4.z, 0.f); h4.w = fmaxf(h4.w, 0.f);

            const float* w2 = W2 + (size_t)r * 8192 + lane * 8;
            float4 oA = make_float4(0.f, 0.f, 0.f, 0.f);
            float4 oB = make_float4(0.f, 0.f, 0.f, 0.f);
            #pragma unroll
            for (int g = 0; g < 4; ++g) {
                float hx = __shfl(h4.x, g);
                float hy = __shfl(h4.y, g);
                float hz = __shfl(h4.z, g);
                float hw = __shfl(h4.w, g);
                float4 wa, wb;
                wa = *reinterpret_cast<const float4*>(w2 + (g * 4 + 0) * 512);
                wb = *reinterpret_cast<const float4*>(w2 + (g * 4 + 0) * 512 + 4);
                oA.x += hx * wa.x; oA.y += hx * wa.y; oA.z += hx * wa.z; oA.w += hx * wa.w;
                oB.x += hx * wb.x; oB.y += hx * wb.y; oB.z += hx * wb.z; oB.w += hx * wb.w;
                wa = *reinterpret_cast<const float4*>(w2 + (g * 4 + 1) * 512);
                wb = *reinterpret_cast<const float4*>(w2 + (g * 4 + 1) * 512 + 4);
                oA.x += hy * wa.x; oA.y += hy * wa.y; oA.z += hy * wa.z; oA.w += hy * wa.w;
                oB.x += hy * wb.x; oB.y += hy * wb.y; oB.z += hy * wb.z; oB.w += hy * wb.w;
                wa = *reinterpret_cast<const float4*>(w2 + (g * 4 + 2) * 512);
                wb = *reinterpret_cast<const float4*>(w2 + (g * 4 + 2) * 512 + 4);
                oA.x += hz * wa.x; oA.y += hz * wa.y; oA.z += hz * wa.z; oA.w += hz * wa.w;
                oB.x += hz * wb.x; oB.y += hz * wb.y; oB.z += hz * wb.z; oB.w += hz * wb.w;
                wa = *reinterpret_cast<const float4*>(w2 + (g * 4 + 3) * 512);
                wb = *reinterpret_cast<const float4*>(w2 + (g * 4 + 3) * 512 + 4);
                oA.x += hw * wa.x; oA.y += hw * wa.y; oA.z += hw * wa.z; oA.w += hw * wa.w;
                oB.x += hw * wb.x; oB.y += hw * wb.y; oB.z += hw * wb.z; oB.w += hw * wb.w;
            }

            float4 z = make_float4(0.f, 0.f, 0.f, 0.f);
            float* ob = outbuf + (size_t)b * 4096 + lane * 8;
            #pragma unroll
            for (int v = 0; v < 8; ++v) {
                bool hit = (v == js);
                *reinterpret_cast<float4*>(ob + v * 512)     = hit ? oA : z;
                *reinterpret_cast<float4*>(ob + v * 512 + 4) = hit ? oB : z;
            }
        }
    }
}

extern "C" void kernel_launch(void* const* d_in, const int* in_sizes, int n_in,
                              void* d_out, int out_size, void* d_ws, size_t ws_size,
                              hipStream_t stream) {
    const float* hidden   = (const float*)d_in[0];
    const float* u_var    = (const float*)d_in[1];
    const float* u_rule   = (const float*)d_in[2];
    const float* Wq       = (const float*)d_in[3];
    const float* bq       = (const float*)d_in[4];
    const float* Wk       = (const float*)d_in[5];
    const float* bk       = (const float*)d_in[6];
    const float* rule_emb = (const float*)d_in[7];
    const float* Wq2      = (const float*)d_in[8];
    const float* bq2      = (const float*)d_in[9];
    const float* Wk2      = (const float*)d_in[10];
    const float* bk2      = (const float*)d_in[11];
    const float* W1       = (const float*)d_in[12];
    const float* W2       = (const float*)d_in[13];

    float* outf = (float*)d_out;

    hipLaunchKernelGGL(fused_kernel, dim3(512), dim3(256), 0, stream,
                       hidden, u_var, u_rule, Wq, bq, Wk, bk,
                       rule_emb, Wk2, bk2, Wq2, bq2, W1, W2, outf);
}

// Round 23
// 95.842 us; speedup vs baseline: 1.2685x; 1.2685x over previous
//
#include <hip/hip_runtime.h>

#define TEMP 5.656854249492380195f   // sqrt(32)
#define EPSG 1e-10f

// Geometry: 4 b's/block (grid 1024). M-tile 32 (4b x 8v), N 64 (q|k),
// K chunk 64, 8 chunks. Micro-tile 2x4 on all 256 threads.
#define XSTR 68                      // x-tile row stride (floats)
#define WSTR 64                      // w-tile row stride

__launch_bounds__(256, 2)
__global__ void fused_kernel(const float* __restrict__ hidden,
                             const float* __restrict__ u_var,
                             const float* __restrict__ u_rule,
                             const float* __restrict__ Wq,
                             const float* __restrict__ bq,
                             const float* __restrict__ Wk,
                             const float* __restrict__ bk,
                             const float* __restrict__ rule_emb,
                             const float* __restrict__ Wk2,
                             const float* __restrict__ bk2,
                             const float* __restrict__ Wq2,
                             const float* __restrict__ bq2,
                             const float* __restrict__ W1,
                             const float* __restrict__ W2,
                             float* __restrict__ outbuf) {
    const int tid = threadIdx.x;
    const int b0  = blockIdx.x * 4;

    // xt [32][XSTR] (8.5 KB) | wt [64][WSTR] (16 KB); scores then comb alias.
    __shared__ float4 smem4[(32 * XSTR + 64 * WSTR) / 4];
    float* smem = reinterpret_cast<float*>(smem4);
    float* xt = smem;
    float* wt = smem + 32 * XSTR;
    __shared__ float4 hm4[512];           // 8 KB hmean; part4 aliases [0:128)
    float* hm = reinterpret_cast<float*>(hm4);
    float4* part4 = hm4;                  // [4 waves][4 bb][8 d4] = 2 KB
    __shared__ float  sk2[512];           // 2 KB
    __shared__ float  s_q2[4][32];
    __shared__ int    ssel[4];
    __shared__ int    s_rsel[4];

    // per-block k2 = rule_emb @ Wk2 + bk2 (identical formula)
    for (int t = tid; t < 512; t += 256) {
        int r = t >> 5, d = t & 31;
        float acc = bk2[d];
        for (int h = 0; h < 64; ++h)
            acc += rule_emb[r * 64 + h] * Wk2[h * 32 + d];
        sk2[t] = acc;
    }

    const int w    = tid >> 6;
    const int lane = tid & 63;
    const int tn   = tid & 15;            // col group (cols tn*4..+3)
    const int tm   = tid >> 4;            // row pair base (rows tm*2, tm*2+1)

    float4 acc0 = make_float4(0.f, 0.f, 0.f, 0.f);
    float4 acc1 = make_float4(0.f, 0.f, 0.f, 0.f);

    for (int c = 0; c < 8; ++c) {
        // stage xt: 512 float4
        #pragma unroll
        for (int p = 0; p < 2; ++p) {
            int f   = p * 256 + tid;
            int row = f >> 4;             // 0..31
            int c4  = f & 15;
            int bb  = row >> 3, v = row & 7;
            float4 val = *reinterpret_cast<const float4*>(
                hidden + (size_t)(b0 + bb) * 4096 + v * 512 + c * 64 + c4 * 4);
            *reinterpret_cast<float4*>(&xt[row * XSTR + c4 * 4]) = val;
        }
        // stage wt: 1024 float4
        #pragma unroll
        for (int p = 0; p < 4; ++p) {
            int f  = p * 256 + tid;
            int k  = f >> 4;              // 0..63
            int n4 = f & 15;
            int h  = c * 64 + k;
            const float* src = (n4 < 8) ? (Wq + h * 32 + n4 * 4)
                                        : (Wk + h * 32 + (n4 - 8) * 4);
            *reinterpret_cast<float4*>(&wt[k * WSTR + n4 * 4]) =
                *reinterpret_cast<const float4*>(src);
        }
        __syncthreads();

        #pragma unroll 4
        for (int k4 = 0; k4 < 16; ++k4) {
            float4 x0 = *reinterpret_cast<const float4*>(&xt[(tm * 2 + 0) * XSTR + k4 * 4]);
            float4 x1 = *reinterpret_cast<const float4*>(&xt[(tm * 2 + 1) * XSTR + k4 * 4]);
            float4 w0 = *reinterpret_cast<const float4*>(&wt[(k4 * 4 + 0) * WSTR + tn * 4]);
            float4 w1 = *reinterpret_cast<const float4*>(&wt[(k4 * 4 + 1) * WSTR + tn * 4]);
            float4 w2 = *reinterpret_cast<const float4*>(&wt[(k4 * 4 + 2) * WSTR + tn * 4]);
            float4 w3 = *reinterpret_cast<const float4*>(&wt[(k4 * 4 + 3) * WSTR + tn * 4]);
            acc0.x += x0.x * w0.x + x0.y * w1.x + x0.z * w2.x + x0.w * w3.x;
            acc0.y += x0.x * w0.y + x0.y * w1.y + x0.z * w2.y + x0.w * w3.y;
            acc0.z += x0.x * w0.z + x0.y * w1.z + x0.z * w2.z + x0.w * w3.z;
            acc0.w += x0.x * w0.w + x0.y * w1.w + x0.z * w2.w + x0.w * w3.w;
            acc1.x += x1.x * w0.x + x1.y * w1.x + x1.z * w2.x + x1.w * w3.x;
            acc1.y += x1.x * w0.y + x1.y * w1.y + x1.z * w2.y + x1.w * w3.y;
            acc1.z += x1.x * w0.z + x1.y * w1.z + x1.z * w2.z + x1.w * w3.z;
            acc1.w += x1.x * w0.w + x1.y * w1.w + x1.z * w2.w + x1.w * w3.w;
        }

        // hmean partial: bb = tid>>6, one column per lane (v-ascending adds)
        {
            int bb = tid >> 6, hg = tid & 63;
            float m = 0.f;
            #pragma unroll
            for (int v = 0; v < 8; ++v) m += xt[(bb * 8 + v) * XSTR + hg];
            hm[bb * 512 + c * 64 + hg] = m * 0.125f;
        }
        __syncthreads();
    }

    // epilogue: bias + scores to LDS (aliases xt region)
    {
        const float* bsrc = (tn < 8) ? (bq + tn * 4) : (bk + (tn - 8) * 4);
        float4 bias4 = *reinterpret_cast<const float4*>(bsrc);
        float4 r0, r1;
        r0.x = acc0.x + bias4.x; r0.y = acc0.y + bias4.y;
        r0.z = acc0.z + bias4.z; r0.w = acc0.w + bias4.w;
        r1.x = acc1.x + bias4.x; r1.y = acc1.y + bias4.y;
        r1.z = acc1.z + bias4.z; r1.w = acc1.w + bias4.w;
        float* sq = smem;
        *reinterpret_cast<float4*>(&sq[(tm * 2 + 0) * XSTR + tn * 4]) = r0;
        *reinterpret_cast<float4*>(&sq[(tm * 2 + 1) * XSTR + tn * 4]) = r1;
    }
    __syncthreads();

    // per-wave argmax: wave w -> b0 + w
    {
        const float* sq = smem;
        const int bb = w;
        const int b  = b0 + bb;
        const int i = lane >> 3, j = lane & 7;
        float s = 0.f;
        #pragma unroll
        for (int d4 = 0; d4 < 8; ++d4) {
            float4 qv = *reinterpret_cast<const float4*>(&sq[(bb * 8 + i) * XSTR + d4 * 4]);
            float4 kv = *reinterpret_cast<const float4*>(&sq[(bb * 8 + j) * XSTR + 32 + d4 * 4]);
            s += qv.x * kv.x + qv.y * kv.y + qv.z * kv.z + qv.w * kv.w;
        }
        s /= TEMP;
        float u = u_var[(size_t)b * 64 + lane];
        float g = -logf(-logf(u + EPSG) + EPSG);
        float pm = s + g;
        int idx = lane;
        #pragma unroll
        for (int off = 32; off >= 1; off >>= 1) {
            float pv = __shfl_xor(pm, off);
            int   pi = __shfl_xor(idx, off);
            if (pv > pm || (pv == pm && pi < idx)) { pm = pv; idx = pi; }
        }
        if (lane == 0) ssel[bb] = idx;
    }
    __syncthreads();   // scores consumed; ssel visible

    // ---- stage comb[4][1024] into the dead xt/wt region (16 KB <= 24.5) ---
    {
        float* comb = smem;
        const float4* h4 = reinterpret_cast<const float4*>(hidden);
        #pragma unroll
        for (int p = 0; p < 4; ++p) {
            int f    = p * 256 + tid;      // 1024 float4 total
            int bb   = f >> 8, idx = f & 255;
            int half = idx >> 7, cc = idx & 127;
            int sv   = ssel[bb];
            int row  = half ? (sv >> 3) : (sv & 7);
            reinterpret_cast<float4*>(comb)[bb * 256 + idx] =
                h4[((size_t)(b0 + bb) * 8 + row) * 128 + cc];
        }
    }
    __syncthreads();

    // ---- q2 GEMM (R15/R16-verified 4-b form, FP order preserved) ----
    {
        const float* comb = smem;
        const int d4 = tid & 7, s = tid >> 3;
        float4 qa[4];
        #pragma unroll
        for (int bb = 0; bb < 4; ++bb) qa[bb] = make_float4(0.f, 0.f, 0.f, 0.f);

        for (int kt = 0; kt < 6; ++kt) {
            float4 wv[8];
            #pragma unroll
            for (int j = 0; j < 8; ++j)
                wv[j] = *reinterpret_cast<const float4*>(
                    Wq2 + (size_t)(kt * 256 + s * 8 + j) * 32 + d4 * 4);
            #pragma unroll
            for (int bb = 0; bb < 4; ++bb) {
                const float* xsrc = (kt < 4) ? &comb[bb * 1024 + kt * 256]
                                             : &hm[bb * 512 + (kt - 4) * 256];
                #pragma unroll
                for (int j = 0; j < 8; ++j) {
                    float x = xsrc[s * 8 + j];
                    qa[bb].x += x * wv[j].x;
                    qa[bb].y += x * wv[j].y;
                    qa[bb].z += x * wv[j].z;
                    qa[bb].w += x * wv[j].w;
                }
            }
        }
        #pragma unroll
        for (int off = 8; off < 64; off <<= 1) {
            #pragma unroll
            for (int bb = 0; bb < 4; ++bb) {
                qa[bb].x += __shfl_xor(qa[bb].x, off);
                qa[bb].y += __shfl_xor(qa[bb].y, off);
                qa[bb].z += __shfl_xor(qa[bb].z, off);
                qa[bb].w += __shfl_xor(qa[bb].w, off);
            }
        }
        __syncthreads();   // hm fully consumed by ALL threads before aliasing
        if ((s & 7) == 0) {
            #pragma unroll
            for (int bb = 0; bb < 4; ++bb)
                part4[(size_t)(tid >> 6) * 32 + bb * 8 + d4] = qa[bb];
        }
    }
    __syncthreads();
    if (tid < 128) {
        const int bb = tid >> 5, col = tid & 31;
        float q2 = bq2[col];
        #pragma unroll
        for (int wv2 = 0; wv2 < 4; ++wv2) {
            const float* pf = reinterpret_cast<const float*>(
                &part4[(size_t)wv2 * 32 + bb * 8 + (col >> 2)]);
            q2 += pf[col & 3];
        }
        s_q2[bb][col] = q2;
    }
    __syncthreads();
    if (tid < 64) {
        const int bb = tid >> 4, r = tid & 15;
        const int b = b0 + bb;
        float sc = 0.f;
        #pragma unroll
        for (int d = 0; d < 32; ++d) sc += s_q2[bb][d] * sk2[r * 32 + d];
        sc /= TEMP;
        float u = u_rule[(size_t)b * 16 + r];
        float g = -logf(-logf(u + EPSG) + EPSG);
        float pm = sc + g;
        int idx = r;
        #pragma unroll
        for (int off = 8; off >= 1; off >>= 1) {
            float pv = __shfl_xor(pm, off, 16);
            int   pi = __shfl_xor(idx, off, 16);
            if (pv > pm || (pv == pm && pi < idx)) { pm = pv; idx = pi; }
        }
        if (r == 0) s_rsel[bb] = idx;
    }
    __syncthreads();

    // ---- Phase C: MLP + output write; wave w owns b0+w (R21-verified) ----
    {
        const float* comb = smem;
        const int bb = w;
        const int b  = b0 + bb;
        const int sv = ssel[bb];
        const int js = sv & 7;
        const int r  = s_rsel[bb];

        const int e4 = lane & 3;
        const int s  = lane >> 2;
        const float* cb  = comb + bb * 1024;
        const float* w1p = W1 + (size_t)r * 16384 + e4 * 4;

        float4 h4 = make_float4(0.f, 0.f, 0.f, 0.f);
        #pragma unroll 8
        for (int i = 0; i < 64; ++i) {
            int rr = i * 16 + s;
            float cv = cb[rr];
            float4 wv4 = *reinterpret_cast<const float4*>(w1p + (size_t)rr * 16);
            h4.x += cv * wv4.x; h4.y += cv * wv4.y;
            h4.z += cv * wv4.z; h4.w += cv * wv4.w;
        }
        #pragma unroll
        for (int off = 4; off <= 32; off <<= 1) {
            h4.x += __shfl_xor(h4.x, off);
            h4.y += __shfl_xor(h4.y, off);
            h4.z += __shfl_xor(h4.z, off);
            h4.w += __shfl_xor(h4.w, off);
        }
        h4.x = fmaxf(h4.x, 0.f); h4.y = fmaxf(h4.y, 0.f);
        h4.z = fmaxf(h4.z, 0.f); h4.w = fmaxf(h4.w, 0.f);

        const float* w2 = W2 + (size_t)r * 8192 + lane * 8;
        float4 oA = make_float4(0.f, 0.f, 0.f, 0.f);
        float4 oB = make_float4(0.f, 0.f, 0.f, 0.f);
        #pragma unroll
        for (int g = 0; g < 4; ++g) {
            float hx = __shfl(h4.x, g);
            float hy = __shfl(h4.y, g);
            float hz = __shfl(h4.z, g);
            float hw = __shfl(h4.w, g);
            float4 wa, wb;
            wa = *reinterpret_cast<const float4*>(w2 + (g * 4 + 0) * 512);
            wb = *reinterpret_cast<const float4*>(w2 + (g * 4 + 0) * 512 + 4);
            oA.x += hx * wa.x; oA.y += hx * wa.y; oA.z += hx * wa.z; oA.w += hx * wa.w;
            oB.x += hx * wb.x; oB.y += hx * wb.y; oB.z += hx * wb.z; oB.w += hx * wb.w;
            wa = *reinterpret_cast<const float4*>(w2 + (g * 4 + 1) * 512);
            wb = *reinterpret_cast<const float4*>(w2 + (g * 4 + 1) * 512 + 4);
            oA.x += hy * wa.x; oA.y += hy * wa.y; oA.z += hy * wa.z; oA.w += hy * wa.w;
            oB.x += hy * wb.x; oB.y += hy * wb.y; oB.z += hy * wb.z; oB.w += hy * wb.w;
            wa = *reinterpret_cast<const float4*>(w2 + (g * 4 + 2) * 512);
            wb = *reinterpret_cast<const float4*>(w2 + (g * 4 + 2) * 512 + 4);
            oA.x += hz * wa.x; oA.y += hz * wa.y; oA.z += hz * wa.z; oA.w += hz * wa.w;
            oB.x += hz * wb.x; oB.y += hz * wb.y; oB.z += hz * wb.z; oB.w += hz * wb.w;
            wa = *reinterpret_cast<const float4*>(w2 + (g * 4 + 3) * 512);
            wb = *reinterpret_cast<const float4*>(w2 + (g * 4 + 3) * 512 + 4);
            oA.x += hw * wa.x; oA.y += hw * wa.y; oA.z += hw * wa.z; oA.w += hw * wa.w;
            oB.x += hw * wb.x; oB.y += hw * wb.y; oB.z += hw * wb.z; oB.w += hw * wb.w;
        }

        float4 z = make_float4(0.f, 0.f, 0.f, 0.f);
        float* ob = outbuf + (size_t)b * 4096 + lane * 8;
        #pragma unroll
        for (int v = 0; v < 8; ++v) {
            bool hit = (v == js);
            *reinterpret_cast<float4*>(ob + v * 512)     = hit ? oA : z;
            *reinterpret_cast<float4*>(ob + v * 512 + 4) = hit ? oB : z;
        }
    }
}

extern "C" void kernel_launch(void* const* d_in, const int* in_sizes, int n_in,
                              void* d_out, int out_size, void* d_ws, size_t ws_size,
                              hipStream_t stream) {
    const float* hidden   = (const float*)d_in[0];
    const float* u_var    = (const float*)d_in[1];
    const float* u_rule   = (const float*)d_in[2];
    const float* Wq       = (const float*)d_in[3];
    const float* bq       = (const float*)d_in[4];
    const float* Wk       = (const float*)d_in[5];
    const float* bk       = (const float*)d_in[6];
    const float* rule_emb = (const float*)d_in[7];
    const float* Wq2      = (const float*)d_in[8];
    const float* bq2      = (const float*)d_in[9];
    const float* Wk2      = (const float*)d_in[10];
    const float* bk2      = (const float*)d_in[11];
    const float* W1       = (const float*)d_in[12];
    const float* W2       = (const float*)d_in[13];

    float* outf = (float*)d_out;

    hipLaunchKernelGGL(fused_kernel, dim3(1024), dim3(256), 0, stream,
                       hidden, u_var, u_rule, Wq, bq, Wk, bk,
                       rule_emb, Wk2, bk2, Wq2, bq2, W1, W2, outf);
}

// Round 24
// 87.929 us; speedup vs baseline: 1.3826x; 1.0900x over previous
//
#include <hip/hip_runtime.h>

#define TEMP 5.656854249492380195f   // sqrt(32)
#define EPSG 1e-10f

// K1 GEMM geometry: M-tile 64 (8 b x 8 v), N 64 (q|k), K chunk 64, 8 chunks.
#define XSTR 68                      // x-tile row stride (floats)
#define WSTR 64                      // w-tile row stride

// ---------- Single fused kernel (R21 structure) ------------------------------
// Phase A: proj GEMM + pair argmax (frozen R11 FP order, 4x4 micro-tile).
// Phase B: comb staging + q2 GEMM + rule argmax (verbatim R21).
// Phase C: MLP + output write — NEW: both b's of the wave interleaved in the
//          h1 loop for 2x memory-level parallelism (value-identical FP).
__launch_bounds__(256, 2)
__global__ void fused_kernel(const float* __restrict__ hidden,
                             const float* __restrict__ u_var,
                             const float* __restrict__ u_rule,
                             const float* __restrict__ Wq,
                             const float* __restrict__ bq,
                             const float* __restrict__ Wk,
                             const float* __restrict__ bk,
                             const float* __restrict__ rule_emb,
                             const float* __restrict__ Wk2,
                             const float* __restrict__ bk2,
                             const float* __restrict__ Wq2,
                             const float* __restrict__ bq2,
                             const float* __restrict__ W1,
                             const float* __restrict__ W2,
                             float* __restrict__ outbuf) {
    const int tid = threadIdx.x;
    const int b0  = blockIdx.x * 8;

    __shared__ float4 smem4[(64 * XSTR + 64 * WSTR) / 4];   // 33.8 KB
    float* smem = reinterpret_cast<float*>(smem4);
    float* xt = smem;
    float* wt = smem + 64 * XSTR;
    __shared__ float4 hm4[1024];          // 16 KB hmean; part4 aliases [0:256)
    float* hm = reinterpret_cast<float*>(hm4);
    float4* part4 = hm4;                  // 4 KB, live only after hm dies
    __shared__ float  sk2[512];           // 2 KB
    __shared__ float  s_q2[8][32];        // 1 KB
    __shared__ int    ssel[8];
    __shared__ int    s_rsel[8];

    // per-block k2 = rule_emb @ Wk2 + bk2 (identical formula)
    for (int t = tid; t < 512; t += 256) {
        int r = t >> 5, d = t & 31;
        float acc = bk2[d];
        for (int h = 0; h < 64; ++h)
            acc += rule_emb[r * 64 + h] * Wk2[h * 32 + d];
        sk2[t] = acc;
    }

    const int w    = tid >> 6;
    const int lane = tid & 63;
    const int tn   = tid & 15;
    const int tm   = tid >> 4;

    float4 acc0 = make_float4(0.f, 0.f, 0.f, 0.f);
    float4 acc1 = make_float4(0.f, 0.f, 0.f, 0.f);
    float4 acc2 = make_float4(0.f, 0.f, 0.f, 0.f);
    float4 acc3 = make_float4(0.f, 0.f, 0.f, 0.f);

    for (int c = 0; c < 8; ++c) {
        #pragma unroll
        for (int p = 0; p < 4; ++p) {
            int f   = p * 256 + tid;
            int row = f >> 4;
            int c4  = f & 15;
            int bb  = row >> 3, v = row & 7;
            float4 val = *reinterpret_cast<const float4*>(
                hidden + (size_t)(b0 + bb) * 4096 + v * 512 + c * 64 + c4 * 4);
            *reinterpret_cast<float4*>(&xt[row * XSTR + c4 * 4]) = val;
        }
        #pragma unroll
        for (int p = 0; p < 4; ++p) {
            int f  = p * 256 + tid;
            int k  = f >> 4;
            int n4 = f & 15;
            int h  = c * 64 + k;
            const float* src = (n4 < 8) ? (Wq + h * 32 + n4 * 4)
                                        : (Wk + h * 32 + (n4 - 8) * 4);
            *reinterpret_cast<float4*>(&wt[k * WSTR + n4 * 4]) =
                *reinterpret_cast<const float4*>(src);
        }
        __syncthreads();

        #pragma unroll 4
        for (int k4 = 0; k4 < 16; ++k4) {
            float4 x0 = *reinterpret_cast<const float4*>(&xt[(tm * 4 + 0) * XSTR + k4 * 4]);
            float4 x1 = *reinterpret_cast<const float4*>(&xt[(tm * 4 + 1) * XSTR + k4 * 4]);
            float4 x2 = *reinterpret_cast<const float4*>(&xt[(tm * 4 + 2) * XSTR + k4 * 4]);
            float4 x3 = *reinterpret_cast<const float4*>(&xt[(tm * 4 + 3) * XSTR + k4 * 4]);
            float4 w0 = *reinterpret_cast<const float4*>(&wt[(k4 * 4 + 0) * WSTR + tn * 4]);
            float4 w1 = *reinterpret_cast<const float4*>(&wt[(k4 * 4 + 1) * WSTR + tn * 4]);
            float4 w2 = *reinterpret_cast<const float4*>(&wt[(k4 * 4 + 2) * WSTR + tn * 4]);
            float4 w3 = *reinterpret_cast<const float4*>(&wt[(k4 * 4 + 3) * WSTR + tn * 4]);
            acc0.x += x0.x * w0.x + x0.y * w1.x + x0.z * w2.x + x0.w * w3.x;
            acc0.y += x0.x * w0.y + x0.y * w1.y + x0.z * w2.y + x0.w * w3.y;
            acc0.z += x0.x * w0.z + x0.y * w1.z + x0.z * w2.z + x0.w * w3.z;
            acc0.w += x0.x * w0.w + x0.y * w1.w + x0.z * w2.w + x0.w * w3.w;
            acc1.x += x1.x * w0.x + x1.y * w1.x + x1.z * w2.x + x1.w * w3.x;
            acc1.y += x1.x * w0.y + x1.y * w1.y + x1.z * w2.y + x1.w * w3.y;
            acc1.z += x1.x * w0.z + x1.y * w1.z + x1.z * w2.z + x1.w * w3.z;
            acc1.w += x1.x * w0.w + x1.y * w1.w + x1.z * w2.w + x1.w * w3.w;
            acc2.x += x2.x * w0.x + x2.y * w1.x + x2.z * w2.x + x2.w * w3.x;
            acc2.y += x2.x * w0.y + x2.y * w1.y + x2.z * w2.y + x2.w * w3.y;
            acc2.z += x2.x * w0.z + x2.y * w1.z + x2.z * w2.z + x2.w * w3.z;
            acc2.w += x2.x * w0.w + x2.y * w1.w + x2.z * w2.w + x2.w * w3.w;
            acc3.x += x3.x * w0.x + x3.y * w1.x + x3.z * w2.x + x3.w * w3.x;
            acc3.y += x3.x * w0.y + x3.y * w1.y + x3.z * w2.y + x3.w * w3.y;
            acc3.z += x3.x * w0.z + x3.y * w1.z + x3.z * w2.z + x3.w * w3.z;
            acc3.w += x3.x * w0.w + x3.y * w1.w + x3.z * w2.w + x3.w * w3.w;
        }

        // hmean partial -> LDS (same adds/order as frozen kernel)
        {
            int bb = tid >> 5, hg = tid & 31;
            float m0 = 0.f, m1 = 0.f;
            #pragma unroll
            for (int v = 0; v < 8; ++v) {
                float2 x2 = *reinterpret_cast<const float2*>(&xt[(bb * 8 + v) * XSTR + hg * 2]);
                m0 += x2.x; m1 += x2.y;
            }
            hm[bb * 512 + c * 64 + hg * 2]     = m0 * 0.125f;
            hm[bb * 512 + c * 64 + hg * 2 + 1] = m1 * 0.125f;
        }
        __syncthreads();
    }

    {
        const float* bsrc = (tn < 8) ? (bq + tn * 4) : (bk + (tn - 8) * 4);
        float4 bias4 = *reinterpret_cast<const float4*>(bsrc);
        float4 r0, r1, r2, r3;
        r0.x = acc0.x + bias4.x; r0.y = acc0.y + bias4.y; r0.z = acc0.z + bias4.z; r0.w = acc0.w + bias4.w;
        r1.x = acc1.x + bias4.x; r1.y = acc1.y + bias4.y; r1.z = acc1.z + bias4.z; r1.w = acc1.w + bias4.w;
        r2.x = acc2.x + bias4.x; r2.y = acc2.y + bias4.y; r2.z = acc2.z + bias4.z; r2.w = acc2.w + bias4.w;
        r3.x = acc3.x + bias4.x; r3.y = acc3.y + bias4.y; r3.z = acc3.z + bias4.z; r3.w = acc3.w + bias4.w;
        float* sq = smem;
        *reinterpret_cast<float4*>(&sq[(tm * 4 + 0) * XSTR + tn * 4]) = r0;
        *reinterpret_cast<float4*>(&sq[(tm * 4 + 1) * XSTR + tn * 4]) = r1;
        *reinterpret_cast<float4*>(&sq[(tm * 4 + 2) * XSTR + tn * 4]) = r2;
        *reinterpret_cast<float4*>(&sq[(tm * 4 + 3) * XSTR + tn * 4]) = r3;
    }
    __syncthreads();

    {
        const float* sq = smem;
        #pragma unroll
        for (int half = 0; half < 2; ++half) {
            const int bb = w + half * 4;
            const int b  = b0 + bb;
            const int i = lane >> 3, j = lane & 7;
            float s = 0.f;
            #pragma unroll
            for (int d4 = 0; d4 < 8; ++d4) {
                float4 qv = *reinterpret_cast<const float4*>(&sq[(bb * 8 + i) * XSTR + d4 * 4]);
                float4 kv = *reinterpret_cast<const float4*>(&sq[(bb * 8 + j) * XSTR + 32 + d4 * 4]);
                s += qv.x * kv.x + qv.y * kv.y + qv.z * kv.z + qv.w * kv.w;
            }
            s /= TEMP;
            float u = u_var[(size_t)b * 64 + lane];
            float g = -logf(-logf(u + EPSG) + EPSG);
            float pm = s + g;
            int idx = lane;
            #pragma unroll
            for (int off = 32; off >= 1; off >>= 1) {
                float pv = __shfl_xor(pm, off);
                int   pi = __shfl_xor(idx, off);
                if (pv > pm || (pv == pm && pi < idx)) { pm = pv; idx = pi; }
            }
            if (lane == 0) ssel[bb] = idx;
        }
    }
    __syncthreads();   // scores consumed; ssel visible

    // ---- stage comb[8][1024] into the dead xt/wt region ----
    {
        float* comb = smem;
        const float4* h4 = reinterpret_cast<const float4*>(hidden);
        #pragma unroll
        for (int p = 0; p < 8; ++p) {
            int f    = p * 256 + tid;      // 2048 float4 total
            int bb   = f >> 8, idx = f & 255;
            int half = idx >> 7, cc = idx & 127;
            int sv   = ssel[bb];
            int row  = half ? (sv >> 3) : (sv & 7);
            reinterpret_cast<float4*>(comb)[bb * 256 + idx] =
                h4[((size_t)(b0 + bb) * 8 + row) * 128 + cc];
        }
    }
    __syncthreads();

    // ---- q2 GEMM (verbatim R18 FP order) + rule argmax ----
    {
        const float* comb = smem;
        const int d4 = tid & 7, s = tid >> 3;
        float4 qa[8];
        #pragma unroll
        for (int bb = 0; bb < 8; ++bb) qa[bb] = make_float4(0.f, 0.f, 0.f, 0.f);

        for (int kt = 0; kt < 6; ++kt) {
            float4 wv[8];
            #pragma unroll
            for (int j = 0; j < 8; ++j)
                wv[j] = *reinterpret_cast<const float4*>(
                    Wq2 + (size_t)(kt * 256 + s * 8 + j) * 32 + d4 * 4);
            #pragma unroll
            for (int bb = 0; bb < 8; ++bb) {
                const float* xsrc = (kt < 4) ? &comb[bb * 1024 + kt * 256]
                                             : &hm[bb * 512 + (kt - 4) * 256];
                #pragma unroll
                for (int j = 0; j < 8; ++j) {
                    float x = xsrc[s * 8 + j];
                    qa[bb].x += x * wv[j].x;
                    qa[bb].y += x * wv[j].y;
                    qa[bb].z += x * wv[j].z;
                    qa[bb].w += x * wv[j].w;
                }
            }
        }
        #pragma unroll
        for (int off = 8; off < 64; off <<= 1) {
            #pragma unroll
            for (int bb = 0; bb < 8; ++bb) {
                qa[bb].x += __shfl_xor(qa[bb].x, off);
                qa[bb].y += __shfl_xor(qa[bb].y, off);
                qa[bb].z += __shfl_xor(qa[bb].z, off);
                qa[bb].w += __shfl_xor(qa[bb].w, off);
            }
        }
        __syncthreads();   // hm fully consumed by ALL threads before aliasing
        if ((s & 7) == 0) {
            #pragma unroll
            for (int bb = 0; bb < 8; ++bb)
                part4[(size_t)(tid >> 6) * 64 + bb * 8 + d4] = qa[bb];
        }
    }
    __syncthreads();
    {
        const int bb = tid >> 5, col = tid & 31;
        float q2 = bq2[col];
        #pragma unroll
        for (int wv2 = 0; wv2 < 4; ++wv2) {
            const float* pf = reinterpret_cast<const float*>(
                &part4[(size_t)wv2 * 64 + bb * 8 + (col >> 2)]);
            q2 += pf[col & 3];
        }
        s_q2[bb][col] = q2;
    }
    __syncthreads();
    if (tid < 128) {
        const int bb = tid >> 4, r = tid & 15;
        const int b = b0 + bb;
        float sc = 0.f;
        #pragma unroll
        for (int d = 0; d < 32; ++d) sc += s_q2[bb][d] * sk2[r * 32 + d];
        sc /= TEMP;
        float u = u_rule[(size_t)b * 16 + r];
        float g = -logf(-logf(u + EPSG) + EPSG);
        float pm = sc + g;
        int idx = r;
        #pragma unroll
        for (int off = 8; off >= 1; off >>= 1) {
            float pv = __shfl_xor(pm, off, 16);
            int   pi = __shfl_xor(idx, off, 16);
            if (pv > pm || (pv == pm && pi < idx)) { pm = pv; idx = pi; }
        }
        if (r == 0) s_rsel[bb] = idx;
    }
    __syncthreads();

    // ---- Phase C: MLP + output write; wave w owns bb = w and w+4 ----------
    // NEW: both b's' h1 loops interleaved -> 2x loads in flight. Per-element
    // FP chains identical to R21 (same i order per h element).
    {
        const float* comb = smem;
        const int bbA = w, bbB = w + 4;
        const int svA = ssel[bbA], svB = ssel[bbB];
        const int jsA = svA & 7,  jsB = svB & 7;
        const int rA  = s_rsel[bbA], rB = s_rsel[bbB];

        const int e4 = lane & 3;
        const int s  = lane >> 2;
        const float* cbA  = comb + bbA * 1024;
        const float* cbB  = comb + bbB * 1024;
        const float* w1pA = W1 + (size_t)rA * 16384 + e4 * 4;
        const float* w1pB = W1 + (size_t)rB * 16384 + e4 * 4;

        float4 hA = make_float4(0.f, 0.f, 0.f, 0.f);
        float4 hB = make_float4(0.f, 0.f, 0.f, 0.f);
        #pragma unroll 4
        for (int i = 0; i < 64; ++i) {
            int rr = i * 16 + s;
            float cvA = cbA[rr];
            float cvB = cbB[rr];
            float4 wA = *reinterpret_cast<const float4*>(w1pA + (size_t)rr * 16);
            float4 wB = *reinterpret_cast<const float4*>(w1pB + (size_t)rr * 16);
            hA.x += cvA * wA.x; hA.y += cvA * wA.y;
            hA.z += cvA * wA.z; hA.w += cvA * wA.w;
            hB.x += cvB * wB.x; hB.y += cvB * wB.y;
            hB.z += cvB * wB.z; hB.w += cvB * wB.w;
        }
        #pragma unroll
        for (int off = 4; off <= 32; off <<= 1) {
            hA.x += __shfl_xor(hA.x, off); hA.y += __shfl_xor(hA.y, off);
            hA.z += __shfl_xor(hA.z, off); hA.w += __shfl_xor(hA.w, off);
            hB.x += __shfl_xor(hB.x, off); hB.y += __shfl_xor(hB.y, off);
            hB.z += __shfl_xor(hB.z, off); hB.w += __shfl_xor(hB.w, off);
        }
        hA.x = fmaxf(hA.x, 0.f); hA.y = fmaxf(hA.y, 0.f);
        hA.z = fmaxf(hA.z, 0.f); hA.w = fmaxf(hA.w, 0.f);
        hB.x = fmaxf(hB.x, 0.f); hB.y = fmaxf(hB.y, 0.f);
        hB.z = fmaxf(hB.z, 0.f); hB.w = fmaxf(hB.w, 0.f);

        #pragma unroll
        for (int half = 0; half < 2; ++half) {
            const int b  = b0 + (half ? bbB : bbA);
            const int js = half ? jsB : jsA;
            const int r  = half ? rB : rA;
            float4 h4v   = half ? hB : hA;

            const float* w2 = W2 + (size_t)r * 8192 + lane * 8;
            float4 oA = make_float4(0.f, 0.f, 0.f, 0.f);
            float4 oB = make_float4(0.f, 0.f, 0.f, 0.f);
            #pragma unroll
            for (int g = 0; g < 4; ++g) {
                float hx = __shfl(h4v.x, g);
                float hy = __shfl(h4v.y, g);
                float hz = __shfl(h4v.z, g);
                float hw = __shfl(h4v.w, g);
                float4 wa, wb;
                wa = *reinterpret_cast<const float4*>(w2 + (g * 4 + 0) * 512);
                wb = *reinterpret_cast<const float4*>(w2 + (g * 4 + 0) * 512 + 4);
                oA.x += hx * wa.x; oA.y += hx * wa.y; oA.z += hx * wa.z; oA.w += hx * wa.w;
                oB.x += hx * wb.x; oB.y += hx * wb.y; oB.z += hx * wb.z; oB.w += hx * wb.w;
                wa = *reinterpret_cast<const float4*>(w2 + (g * 4 + 1) * 512);
                wb = *reinterpret_cast<const float4*>(w2 + (g * 4 + 1) * 512 + 4);
                oA.x += hy * wa.x; oA.y += hy * wa.y; oA.z += hy * wa.z; oA.w += hy * wa.w;
                oB.x += hy * wb.x; oB.y += hy * wb.y; oB.z += hy * wb.z; oB.w += hy * wb.w;
                wa = *reinterpret_cast<const float4*>(w2 + (g * 4 + 2) * 512);
                wb = *reinterpret_cast<const float4*>(w2 + (g * 4 + 2) * 512 + 4);
                oA.x += hz * wa.x; oA.y += hz * wa.y; oA.z += hz * wa.z; oA.w += hz * wa.w;
                oB.x += hz * wb.x; oB.y += hz * wb.y; oB.z += hz * wb.z; oB.w += hz * wb.w;
                wa = *reinterpret_cast<const float4*>(w2 + (g * 4 + 3) * 512);
                wb = *reinterpret_cast<const float4*>(w2 + (g * 4 + 3) * 512 + 4);
                oA.x += hw * wa.x; oA.y += hw * wa.y; oA.z += hw * wa.z; oA.w += hw * wa.w;
                oB.x += hw * wb.x; oB.y += hw * wb.y; oB.z += hw * wb.z; oB.w += hw * wb.w;
            }

            float4 z = make_float4(0.f, 0.f, 0.f, 0.f);
            float* ob = outbuf + (size_t)b * 4096 + lane * 8;
            #pragma unroll
            for (int v = 0; v < 8; ++v) {
                bool hit = (v == js);
                *reinterpret_cast<float4*>(ob + v * 512)     = hit ? oA : z;
                *reinterpret_cast<float4*>(ob + v * 512 + 4) = hit ? oB : z;
            }
        }
    }
}

extern "C" void kernel_launch(void* const* d_in, const int* in_sizes, int n_in,
                              void* d_out, int out_size, void* d_ws, size_t ws_size,
                              hipStream_t stream) {
    const float* hidden   = (const float*)d_in[0];
    const float* u_var    = (const float*)d_in[1];
    const float* u_rule   = (const float*)d_in[2];
    const float* Wq       = (const float*)d_in[3];
    const float* bq       = (const float*)d_in[4];
    const float* Wk       = (const float*)d_in[5];
    const float* bk       = (const float*)d_in[6];
    const float* rule_emb = (const float*)d_in[7];
    const float* Wq2      = (const float*)d_in[8];
    const float* bq2      = (const float*)d_in[9];
    const float* Wk2      = (const float*)d_in[10];
    const float* bk2      = (const float*)d_in[11];
    const float* W1       = (const float*)d_in[12];
    const float* W2       = (const float*)d_in[13];

    float* outf = (float*)d_out;

    hipLaunchKernelGGL(fused_kernel, dim3(512), dim3(256), 0, stream,
                       hidden, u_var, u_rule, Wq, bq, Wk, bk,
                       rule_emb, Wk2, bk2, Wq2, bq2, W1, W2, outf);
}

// Round 25
// 74.875 us; speedup vs baseline: 1.6237x; 1.1743x over previous
//
#include <hip/hip_runtime.h>

#define TEMP 5.656854249492380195f   // sqrt(32)
#define EPSG 1e-10f

// K1 GEMM geometry: M-tile 64 (8 b x 8 v), N 64 (q|k), K chunk 64, 8 chunks.
#define XSTR 68                      // x-tile row stride (floats)
#define WSTR 64                      // w-tile row stride

// ---------- Single fused kernel (R21 structure + early zero-prefill) --------
// Phase A: proj GEMM + pair argmax (frozen R11 FP order, 4x4 micro-tile).
// Phase B: comb staging + q2 GEMM + rule argmax (verbatim R21).
// Phase C: MLP (verbatim R21) + js-slot-only write; the zero slots were
//          prefilled at kernel start (stores drain under the GEMM).
__launch_bounds__(256, 2)
__global__ void fused_kernel(const float* __restrict__ hidden,
                             const float* __restrict__ u_var,
                             const float* __restrict__ u_rule,
                             const float* __restrict__ Wq,
                             const float* __restrict__ bq,
                             const float* __restrict__ Wk,
                             const float* __restrict__ bk,
                             const float* __restrict__ rule_emb,
                             const float* __restrict__ Wk2,
                             const float* __restrict__ bk2,
                             const float* __restrict__ Wq2,
                             const float* __restrict__ bq2,
                             const float* __restrict__ W1,
                             const float* __restrict__ W2,
                             float* __restrict__ outbuf) {
    const int tid = threadIdx.x;
    const int b0  = blockIdx.x * 8;

    __shared__ float4 smem4[(64 * XSTR + 64 * WSTR) / 4];   // 33.8 KB
    float* smem = reinterpret_cast<float*>(smem4);
    float* xt = smem;
    float* wt = smem + 64 * XSTR;
    __shared__ float4 hm4[1024];          // 16 KB hmean; part4 aliases [0:256)
    float* hm = reinterpret_cast<float*>(hm4);
    float4* part4 = hm4;                  // 4 KB, live only after hm dies
    __shared__ float  sk2[512];           // 2 KB
    __shared__ float  s_q2[8][32];        // 1 KB
    __shared__ int    ssel[8];
    __shared__ int    s_rsel[8];

    // ---- early zero-prefill of this block's output region (8 b x 16 KB) ---
    // Independent of all compute; stores drain under the GEMM. The final
    // js-slot write (Phase C) is ordered after via __syncthreads fences.
    {
        float4 z = make_float4(0.f, 0.f, 0.f, 0.f);
        float4* ob4 = reinterpret_cast<float4*>(outbuf + (size_t)b0 * 4096);
        #pragma unroll
        for (int p = 0; p < 32; ++p)
            ob4[p * 256 + tid] = z;
    }

    // per-block k2 = rule_emb @ Wk2 + bk2 (identical formula)
    for (int t = tid; t < 512; t += 256) {
        int r = t >> 5, d = t & 31;
        float acc = bk2[d];
        for (int h = 0; h < 64; ++h)
            acc += rule_emb[r * 64 + h] * Wk2[h * 32 + d];
        sk2[t] = acc;
    }

    const int w    = tid >> 6;
    const int lane = tid & 63;
    const int tn   = tid & 15;
    const int tm   = tid >> 4;

    float4 acc0 = make_float4(0.f, 0.f, 0.f, 0.f);
    float4 acc1 = make_float4(0.f, 0.f, 0.f, 0.f);
    float4 acc2 = make_float4(0.f, 0.f, 0.f, 0.f);
    float4 acc3 = make_float4(0.f, 0.f, 0.f, 0.f);

    for (int c = 0; c < 8; ++c) {
        #pragma unroll
        for (int p = 0; p < 4; ++p) {
            int f   = p * 256 + tid;
            int row = f >> 4;
            int c4  = f & 15;
            int bb  = row >> 3, v = row & 7;
            float4 val = *reinterpret_cast<const float4*>(
                hidden + (size_t)(b0 + bb) * 4096 + v * 512 + c * 64 + c4 * 4);
            *reinterpret_cast<float4*>(&xt[row * XSTR + c4 * 4]) = val;
        }
        #pragma unroll
        for (int p = 0; p < 4; ++p) {
            int f  = p * 256 + tid;
            int k  = f >> 4;
            int n4 = f & 15;
            int h  = c * 64 + k;
            const float* src = (n4 < 8) ? (Wq + h * 32 + n4 * 4)
                                        : (Wk + h * 32 + (n4 - 8) * 4);
            *reinterpret_cast<float4*>(&wt[k * WSTR + n4 * 4]) =
                *reinterpret_cast<const float4*>(src);
        }
        __syncthreads();

        #pragma unroll 4
        for (int k4 = 0; k4 < 16; ++k4) {
            float4 x0 = *reinterpret_cast<const float4*>(&xt[(tm * 4 + 0) * XSTR + k4 * 4]);
            float4 x1 = *reinterpret_cast<const float4*>(&xt[(tm * 4 + 1) * XSTR + k4 * 4]);
            float4 x2 = *reinterpret_cast<const float4*>(&xt[(tm * 4 + 2) * XSTR + k4 * 4]);
            float4 x3 = *reinterpret_cast<const float4*>(&xt[(tm * 4 + 3) * XSTR + k4 * 4]);
            float4 w0 = *reinterpret_cast<const float4*>(&wt[(k4 * 4 + 0) * WSTR + tn * 4]);
            float4 w1 = *reinterpret_cast<const float4*>(&wt[(k4 * 4 + 1) * WSTR + tn * 4]);
            float4 w2 = *reinterpret_cast<const float4*>(&wt[(k4 * 4 + 2) * WSTR + tn * 4]);
            float4 w3 = *reinterpret_cast<const float4*>(&wt[(k4 * 4 + 3) * WSTR + tn * 4]);
            acc0.x += x0.x * w0.x + x0.y * w1.x + x0.z * w2.x + x0.w * w3.x;
            acc0.y += x0.x * w0.y + x0.y * w1.y + x0.z * w2.y + x0.w * w3.y;
            acc0.z += x0.x * w0.z + x0.y * w1.z + x0.z * w2.z + x0.w * w3.z;
            acc0.w += x0.x * w0.w + x0.y * w1.w + x0.z * w2.w + x0.w * w3.w;
            acc1.x += x1.x * w0.x + x1.y * w1.x + x1.z * w2.x + x1.w * w3.x;
            acc1.y += x1.x * w0.y + x1.y * w1.y + x1.z * w2.y + x1.w * w3.y;
            acc1.z += x1.x * w0.z + x1.y * w1.z + x1.z * w2.z + x1.w * w3.z;
            acc1.w += x1.x * w0.w + x1.y * w1.w + x1.z * w2.w + x1.w * w3.w;
            acc2.x += x2.x * w0.x + x2.y * w1.x + x2.z * w2.x + x2.w * w3.x;
            acc2.y += x2.x * w0.y + x2.y * w1.y + x2.z * w2.y + x2.w * w3.y;
            acc2.z += x2.x * w0.z + x2.y * w1.z + x2.z * w2.z + x2.w * w3.z;
            acc2.w += x2.x * w0.w + x2.y * w1.w + x2.z * w2.w + x2.w * w3.w;
            acc3.x += x3.x * w0.x + x3.y * w1.x + x3.z * w2.x + x3.w * w3.x;
            acc3.y += x3.x * w0.y + x3.y * w1.y + x3.z * w2.y + x3.w * w3.y;
            acc3.z += x3.x * w0.z + x3.y * w1.z + x3.z * w2.z + x3.w * w3.z;
            acc3.w += x3.x * w0.w + x3.y * w1.w + x3.z * w2.w + x3.w * w3.w;
        }

        // hmean partial -> LDS (same adds/order as frozen kernel)
        {
            int bb = tid >> 5, hg = tid & 31;
            float m0 = 0.f, m1 = 0.f;
            #pragma unroll
            for (int v = 0; v < 8; ++v) {
                float2 x2 = *reinterpret_cast<const float2*>(&xt[(bb * 8 + v) * XSTR + hg * 2]);
                m0 += x2.x; m1 += x2.y;
            }
            hm[bb * 512 + c * 64 + hg * 2]     = m0 * 0.125f;
            hm[bb * 512 + c * 64 + hg * 2 + 1] = m1 * 0.125f;
        }
        __syncthreads();
    }

    {
        const float* bsrc = (tn < 8) ? (bq + tn * 4) : (bk + (tn - 8) * 4);
        float4 bias4 = *reinterpret_cast<const float4*>(bsrc);
        float4 r0, r1, r2, r3;
        r0.x = acc0.x + bias4.x; r0.y = acc0.y + bias4.y; r0.z = acc0.z + bias4.z; r0.w = acc0.w + bias4.w;
        r1.x = acc1.x + bias4.x; r1.y = acc1.y + bias4.y; r1.z = acc1.z + bias4.z; r1.w = acc1.w + bias4.w;
        r2.x = acc2.x + bias4.x; r2.y = acc2.y + bias4.y; r2.z = acc2.z + bias4.z; r2.w = acc2.w + bias4.w;
        r3.x = acc3.x + bias4.x; r3.y = acc3.y + bias4.y; r3.z = acc3.z + bias4.z; r3.w = acc3.w + bias4.w;
        float* sq = smem;
        *reinterpret_cast<float4*>(&sq[(tm * 4 + 0) * XSTR + tn * 4]) = r0;
        *reinterpret_cast<float4*>(&sq[(tm * 4 + 1) * XSTR + tn * 4]) = r1;
        *reinterpret_cast<float4*>(&sq[(tm * 4 + 2) * XSTR + tn * 4]) = r2;
        *reinterpret_cast<float4*>(&sq[(tm * 4 + 3) * XSTR + tn * 4]) = r3;
    }
    __syncthreads();

    {
        const float* sq = smem;
        #pragma unroll
        for (int half = 0; half < 2; ++half) {
            const int bb = w + half * 4;
            const int b  = b0 + bb;
            const int i = lane >> 3, j = lane & 7;
            float s = 0.f;
            #pragma unroll
            for (int d4 = 0; d4 < 8; ++d4) {
                float4 qv = *reinterpret_cast<const float4*>(&sq[(bb * 8 + i) * XSTR + d4 * 4]);
                float4 kv = *reinterpret_cast<const float4*>(&sq[(bb * 8 + j) * XSTR + 32 + d4 * 4]);
                s += qv.x * kv.x + qv.y * kv.y + qv.z * kv.z + qv.w * kv.w;
            }
            s /= TEMP;
            float u = u_var[(size_t)b * 64 + lane];
            float g = -logf(-logf(u + EPSG) + EPSG);
            float pm = s + g;
            int idx = lane;
            #pragma unroll
            for (int off = 32; off >= 1; off >>= 1) {
                float pv = __shfl_xor(pm, off);
                int   pi = __shfl_xor(idx, off);
                if (pv > pm || (pv == pm && pi < idx)) { pm = pv; idx = pi; }
            }
            if (lane == 0) ssel[bb] = idx;
        }
    }
    __syncthreads();   // scores consumed; ssel visible

    // ---- stage comb[8][1024] into the dead xt/wt region ----
    {
        float* comb = smem;
        const float4* h4 = reinterpret_cast<const float4*>(hidden);
        #pragma unroll
        for (int p = 0; p < 8; ++p) {
            int f    = p * 256 + tid;      // 2048 float4 total
            int bb   = f >> 8, idx = f & 255;
            int half = idx >> 7, cc = idx & 127;
            int sv   = ssel[bb];
            int row  = half ? (sv >> 3) : (sv & 7);
            reinterpret_cast<float4*>(comb)[bb * 256 + idx] =
                h4[((size_t)(b0 + bb) * 8 + row) * 128 + cc];
        }
    }
    __syncthreads();

    // ---- q2 GEMM (verbatim R18 FP order) + rule argmax ----
    {
        const float* comb = smem;
        const int d4 = tid & 7, s = tid >> 3;
        float4 qa[8];
        #pragma unroll
        for (int bb = 0; bb < 8; ++bb) qa[bb] = make_float4(0.f, 0.f, 0.f, 0.f);

        for (int kt = 0; kt < 6; ++kt) {
            float4 wv[8];
            #pragma unroll
            for (int j = 0; j < 8; ++j)
                wv[j] = *reinterpret_cast<const float4*>(
                    Wq2 + (size_t)(kt * 256 + s * 8 + j) * 32 + d4 * 4);
            #pragma unroll
            for (int bb = 0; bb < 8; ++bb) {
                const float* xsrc = (kt < 4) ? &comb[bb * 1024 + kt * 256]
                                             : &hm[bb * 512 + (kt - 4) * 256];
                #pragma unroll
                for (int j = 0; j < 8; ++j) {
                    float x = xsrc[s * 8 + j];
                    qa[bb].x += x * wv[j].x;
                    qa[bb].y += x * wv[j].y;
                    qa[bb].z += x * wv[j].z;
                    qa[bb].w += x * wv[j].w;
                }
            }
        }
        #pragma unroll
        for (int off = 8; off < 64; off <<= 1) {
            #pragma unroll
            for (int bb = 0; bb < 8; ++bb) {
                qa[bb].x += __shfl_xor(qa[bb].x, off);
                qa[bb].y += __shfl_xor(qa[bb].y, off);
                qa[bb].z += __shfl_xor(qa[bb].z, off);
                qa[bb].w += __shfl_xor(qa[bb].w, off);
            }
        }
        __syncthreads();   // hm fully consumed by ALL threads before aliasing
        if ((s & 7) == 0) {
            #pragma unroll
            for (int bb = 0; bb < 8; ++bb)
                part4[(size_t)(tid >> 6) * 64 + bb * 8 + d4] = qa[bb];
        }
    }
    __syncthreads();
    {
        const int bb = tid >> 5, col = tid & 31;
        float q2 = bq2[col];
        #pragma unroll
        for (int wv2 = 0; wv2 < 4; ++wv2) {
            const float* pf = reinterpret_cast<const float*>(
                &part4[(size_t)wv2 * 64 + bb * 8 + (col >> 2)]);
            q2 += pf[col & 3];
        }
        s_q2[bb][col] = q2;
    }
    __syncthreads();
    if (tid < 128) {
        const int bb = tid >> 4, r = tid & 15;
        const int b = b0 + bb;
        float sc = 0.f;
        #pragma unroll
        for (int d = 0; d < 32; ++d) sc += s_q2[bb][d] * sk2[r * 32 + d];
        sc /= TEMP;
        float u = u_rule[(size_t)b * 16 + r];
        float g = -logf(-logf(u + EPSG) + EPSG);
        float pm = sc + g;
        int idx = r;
        #pragma unroll
        for (int off = 8; off >= 1; off >>= 1) {
            float pv = __shfl_xor(pm, off, 16);
            int   pi = __shfl_xor(idx, off, 16);
            if (pv > pm || (pv == pm && pi < idx)) { pm = pv; idx = pi; }
        }
        if (r == 0) s_rsel[bb] = idx;
    }
    __syncthreads();

    // ---- Phase C: MLP (verbatim R21) + js-slot-only write ----
    {
        const float* comb = smem;
        #pragma unroll
        for (int half = 0; half < 2; ++half) {
            const int bb = w + half * 4;
            const int b  = b0 + bb;
            const int sv = ssel[bb];
            const int js = sv & 7;
            const int r  = s_rsel[bb];

            const int e4 = lane & 3;
            const int s  = lane >> 2;
            const float* cb  = comb + bb * 1024;
            const float* w1p = W1 + (size_t)r * 16384 + e4 * 4;

            float4 h4 = make_float4(0.f, 0.f, 0.f, 0.f);
            #pragma unroll 8
            for (int i = 0; i < 64; ++i) {
                int rr = i * 16 + s;
                float cv = cb[rr];
                float4 wv4 = *reinterpret_cast<const float4*>(w1p + (size_t)rr * 16);
                h4.x += cv * wv4.x; h4.y += cv * wv4.y;
                h4.z += cv * wv4.z; h4.w += cv * wv4.w;
            }
            #pragma unroll
            for (int off = 4; off <= 32; off <<= 1) {
                h4.x += __shfl_xor(h4.x, off);
                h4.y += __shfl_xor(h4.y, off);
                h4.z += __shfl_xor(h4.z, off);
                h4.w += __shfl_xor(h4.w, off);
            }
            h4.x = fmaxf(h4.x, 0.f); h4.y = fmaxf(h4.y, 0.f);
            h4.z = fmaxf(h4.z, 0.f); h4.w = fmaxf(h4.w, 0.f);

            const float* w2 = W2 + (size_t)r * 8192 + lane * 8;
            float4 oA = make_float4(0.f, 0.f, 0.f, 0.f);
            float4 oB = make_float4(0.f, 0.f, 0.f, 0.f);
            #pragma unroll
            for (int g = 0; g < 4; ++g) {
                float hx = __shfl(h4.x, g);
                float hy = __shfl(h4.y, g);
                float hz = __shfl(h4.z, g);
                float hw = __shfl(h4.w, g);
                float4 wa, wb;
                wa = *reinterpret_cast<const float4*>(w2 + (g * 4 + 0) * 512);
                wb = *reinterpret_cast<const float4*>(w2 + (g * 4 + 0) * 512 + 4);
                oA.x += hx * wa.x; oA.y += hx * wa.y; oA.z += hx * wa.z; oA.w += hx * wa.w;
                oB.x += hx * wb.x; oB.y += hx * wb.y; oB.z += hx * wb.z; oB.w += hx * wb.w;
                wa = *reinterpret_cast<const float4*>(w2 + (g * 4 + 1) * 512);
                wb = *reinterpret_cast<const float4*>(w2 + (g * 4 + 1) * 512 + 4);
                oA.x += hy * wa.x; oA.y += hy * wa.y; oA.z += hy * wa.z; oA.w += hy * wa.w;
                oB.x += hy * wb.x; oB.y += hy * wb.y; oB.z += hy * wb.z; oB.w += hy * wb.w;
                wa = *reinterpret_cast<const float4*>(w2 + (g * 4 + 2) * 512);
                wb = *reinterpret_cast<const float4*>(w2 + (g * 4 + 2) * 512 + 4);
                oA.x += hz * wa.x; oA.y += hz * wa.y; oA.z += hz * wa.z; oA.w += hz * wa.w;
                oB.x += hz * wb.x; oB.y += hz * wb.y; oB.z += hz * wb.z; oB.w += hz * wb.w;
                wa = *reinterpret_cast<const float4*>(w2 + (g * 4 + 3) * 512);
                wb = *reinterpret_cast<const float4*>(w2 + (g * 4 + 3) * 512 + 4);
                oA.x += hw * wa.x; oA.y += hw * wa.y; oA.z += hw * wa.z; oA.w += hw * wa.w;
                oB.x += hw * wb.x; oB.y += hw * wb.y; oB.z += hw * wb.z; oB.w += hw * wb.w;
            }

            // js slot only — zeros were prefilled at kernel start
            float* ob = outbuf + (size_t)b * 4096 + js * 512 + lane * 8;
            *reinterpret_cast<float4*>(ob)     = oA;
            *reinterpret_cast<float4*>(ob + 4) = oB;
        }
    }
}

extern "C" void kernel_launch(void* const* d_in, const int* in_sizes, int n_in,
                              void* d_out, int out_size, void* d_ws, size_t ws_size,
                              hipStream_t stream) {
    const float* hidden   = (const float*)d_in[0];
    const float* u_var    = (const float*)d_in[1];
    const float* u_rule   = (const float*)d_in[2];
    const float* Wq       = (const float*)d_in[3];
    const float* bq       = (const float*)d_in[4];
    const float* Wk       = (const float*)d_in[5];
    const float* bk       = (const float*)d_in[6];
    const float* rule_emb = (const float*)d_in[7];
    const float* Wq2      = (const float*)d_in[8];
    const float* bq2      = (const float*)d_in[9];
    const float* Wk2      = (const float*)d_in[10];
    const float* bk2      = (const float*)d_in[11];
    const float* W1       = (const float*)d_in[12];
    const float* W2       = (const float*)d_in[13];

    float* outf = (float*)d_out;

    hipLaunchKernelGGL(fused_kernel, dim3(512), dim3(256), 0, stream,
                       hidden, u_var, u_rule, Wq, bq, Wk, bk,
                       rule_emb, Wk2, bk2, Wq2, bq2, W1, W2, outf);
}